// Round 5
// baseline (265.593 us; speedup 1.0000x reference)
//
#include <hip/hip_runtime.h>
#include <hip/hip_fp16.h>

#define EGO 0.018315638888734179f   // exp(-4)
#define EGE 0.36787944117144233f    // exp(-1)

// =====================================================================
// Fast path: precompute diag-major gathered exp(scores) in FP16, then DP.
// Layout: per (b,p): 64 groups x 16 halves; group g = lane, halves 0-7 = ev
// for slots j=8g..8g+7, halves 8-15 = od. One (b,p) = 2048 B.
// Grid mapping puts ALL blocks of batch b on XCD b%8 (blockIdx%8 round-robin)
// so X[b] stays in the local XCD L2 that the DP block for b will read.
// =====================================================================
__global__ __launch_bounds__(512) void sw_pre_kernel(const float* __restrict__ pred,
                                                     const int* __restrict__ tgt,
                                                     __half* __restrict__ X) {
  const int q = (int)blockIdx.x;
  const int b = (q & 7) | ((q >> 12) << 3);   // b%8 == q%8 -> XCD affinity
  const int p = (q >> 3) & 511;
  const int j = (int)threadIdx.x;
  const int a = 255 - j + p;
  const int c = p + j - 255;
  const bool av = (a >= 0) && (a < 512);
  float evn = 0.0f, odd = 0.0f;
  if (av && c >= 0 && c < 512)
    evn = __expf(pred[(((b << 9) + a) << 2) + tgt[(b << 9) + c]]);
  if (av && (c + 1) >= 0 && (c + 1) < 512)
    odd = __expf(pred[(((b << 9) + a) << 2) + tgt[(b << 9) + c + 1]]);
  const size_t idx = (((size_t)((b << 9) | p)) << 10) + ((size_t)(j >> 3) << 4) + (j & 7);
  X[idx] = __float2half(evn);
  X[idx + 8] = __float2half(odd);
}

// One wave per batch. Slot j = 8*lane + s. Exp-domain DP, all state in registers.
// es stream from X (fp16), prefetched 4 p-iters deep into uint4 regs.
__global__ __launch_bounds__(64) void sw_dp_fast(const __half* __restrict__ X,
                                                 float* __restrict__ partials) {
  const int lane = (int)threadIdx.x;
  const int b = (int)blockIdx.x;
  const char* Xbase = (const char*)X + ((size_t)b << 20);   // 1 MiB per batch

  int PE_[8], PO_[8];
  float U[8], D[8], SE[8], SEpa[8], SO[8], SOpa[8], RC[8], DC[8], RCe[8];
  #pragma unroll
  for (int s = 0; s < 8; ++s) {
    const int j = 8 * lane + s;
    const int e1 = 255 + j, e2 = 765 - j, o2 = 764 - j;
    PE_[s] = e1 < e2 ? e1 : e2;
    PO_[s] = e1 < o2 ? e1 : o2;
    U[s] = D[s] = SE[s] = SEpa[s] = SO[s] = SOpa[s] = RC[s] = 0.0f;
  }
  float acc[4] = {0.0f, 0.0f, 0.0f, 0.0f};
  float one = 1.0f;      // 2^-Etot
  int Etot = 0;
  const int lanem1 = (lane + 63) & 63;
  const int lanep1 = (lane + 1) & 63;
  const bool is0 = (lane == 0);
  const bool is63 = (lane == 63);

  uint4 evb[4], odb[4];

#define LOADP(par, p) do {                                                    \
    const char* q_ = Xbase + (((size_t)(p)) << 11) + (lane << 5);             \
    evb[par] = *(const uint4*)q_;                                             \
    odb[par] = *(const uint4*)(q_ + 16);                                      \
  } while (0)

// EVENS: descending s so the shuffled rcS (bpermute) is consumed LAST.
#define EVENS(par, p) do {                                                    \
    float rcS = __shfl(RC[7], lanem1, 64);                                    \
    const __half2* eh_ = (const __half2*)&evb[par];                           \
    _Pragma("unroll")                                                         \
    for (int ss = 0; ss < 8; ++ss) {                                          \
      const int s = 7 - ss;                                                   \
      const __half2 hp_ = eh_[s >> 1];                                        \
      const float raw = (s & 1) ? __high2float(hp_) : __low2float(hp_);       \
      const float right = (s == 0) ? (is0 ? 0.0f : rcS) : RC[s - 1];          \
      const float dn = U[s] * EGO + D[s] * EGE;                               \
      const bool v = ((p) <= PE_[s]);                                         \
      acc[s & 3] += SEpa[s] * raw;                                            \
      const float esg = v ? raw : 0.0f;                                       \
      const float al = esg * (SE[s] + one);                                   \
      const float Un = al + right;                                            \
      const float s3 = Un + dn;                                               \
      SE[s] = s3; SEpa[s] = v ? s3 : 0.0f;                                    \
      U[s] = Un; D[s] = dn;                                                   \
      float dc = Un * EGO + dn * EGE;                                         \
      if (s == 7) dc = is63 ? 0.0f : dc;   /* slot 511 is phantom */          \
      DC[s] = dc;                                                             \
      RCe[s] = al * EGO + right * EGE;                                        \
    }                                                                         \
  } while (0)

// ODDS: ascending s so the shuffled dcS is consumed LAST (s==7).
#define ODDS(par, p) do {                                                     \
    float dcS = __shfl(DC[0], lanep1, 64);                                    \
    const __half2* oh_ = (const __half2*)&odb[par];                           \
    _Pragma("unroll")                                                         \
    for (int s = 0; s < 8; ++s) {                                             \
      const __half2 hp_ = oh_[s >> 1];                                        \
      const float raw = (s & 1) ? __high2float(hp_) : __low2float(hp_);       \
      const float dnv = (s == 7) ? (is63 ? 0.0f : dcS) : DC[s + 1];           \
      const float right = RCe[s];                                             \
      const bool v = ((p) <= PO_[s]);                                         \
      acc[s & 3] += SOpa[s] * raw;                                            \
      const float esg = v ? raw : 0.0f;                                       \
      const float al = esg * (SO[s] + one);                                   \
      const float Un = al + right;                                            \
      const float s3 = Un + dnv;                                              \
      SO[s] = s3; SOpa[s] = v ? s3 : 0.0f;                                    \
      U[s] = Un; D[s] = dnv;                                                  \
      RC[s] = al * EGO + right * EGE;                                         \
    }                                                                         \
  } while (0)

  LOADP(0, 0); LOADP(1, 1); LOADP(2, 2); LOADP(3, 3);

  for (int qq = 0; qq < 127; ++qq) {
    const int p0 = qq << 2;
    EVENS(0, p0);     ODDS(0, p0);     LOADP(0, p0 + 4);
    EVENS(1, p0 + 1); ODDS(1, p0 + 1); LOADP(1, p0 + 5);
    EVENS(2, p0 + 2); ODDS(2, p0 + 2); LOADP(2, p0 + 6);
    EVENS(3, p0 + 3); ODDS(3, p0 + 3); LOADP(3, p0 + 7);
    if ((qq & 3) == 3) {
      float mx = fmaxf(SE[0], SO[0]);
      #pragma unroll
      for (int s = 1; s < 8; ++s) mx = fmaxf(mx, fmaxf(SE[s], SO[s]));
      #pragma unroll
      for (int off = 1; off < 64; off <<= 1) mx = fmaxf(mx, __shfl_xor(mx, off, 64));
      const int ex = (int)((__float_as_uint(mx) >> 23) & 0xff);
      const float sc = __uint_as_float((unsigned)(253 - ex) << 23);  // 2^(126-ex)
      Etot += ex - 126;
      #pragma unroll
      for (int s = 0; s < 8; ++s) {
        U[s] *= sc; D[s] *= sc; RC[s] *= sc;
        SE[s] *= sc; SEpa[s] *= sc; SO[s] *= sc; SOpa[s] *= sc;
      }
      acc[0] *= sc; acc[1] *= sc; acc[2] *= sc; acc[3] *= sc;
      one *= sc;
    }
  }
  // tail: p = 508, 509, 510 (no further loads)
  EVENS(0, 508); ODDS(0, 508);
  EVENS(1, 509); ODDS(1, 509);
  EVENS(2, 510); ODDS(2, 510);
  // epilogue p = 511: pa-only, consumes buffer 3
  {
    const __half2* eh_ = (const __half2*)&evb[3];
    const __half2* oh_ = (const __half2*)&odb[3];
    #pragma unroll
    for (int s = 0; s < 8; ++s) {
      const __half2 he_ = eh_[s >> 1], ho_ = oh_[s >> 1];
      const float re = (s & 1) ? __high2float(he_) : __low2float(he_);
      const float ro = (s & 1) ? __high2float(ho_) : __low2float(ho_);
      acc[s & 3] += SEpa[s] * re;
      acc[s & 3] += SOpa[s] * ro;
    }
  }

  float atot = (acc[0] + acc[1]) + (acc[2] + acc[3]);
  #pragma unroll
  for (int off = 1; off < 64; off <<= 1) atot += __shfl_xor(atot, off, 64);
  if (lane == 0) partials[b] = __logf(atot) + (float)Etot * 0.69314718055994531f;

#undef LOADP
#undef EVENS
#undef ODDS
}

// =====================================================================
// Fallback (R3, validated absmax 0.0): used when ws_size is too small.
// =====================================================================
__global__ __launch_bounds__(64) void sw_dp_kernel(const float* __restrict__ pred,
                                                   const int* __restrict__ tgt,
                                                   float* __restrict__ partials) {
  __shared__ float EPT[5120];
  __shared__ int   TG[1024];

  const int lane = (int)threadIdx.x;
  const int b = (int)blockIdx.x;

  #pragma unroll
  for (int k = 0; k < 80; ++k) EPT[lane + 64 * k] = 0.0f;
  #pragma unroll
  for (int k = 0; k < 16; ++k) {
    const int lc = lane + 64 * k;
    int vv = 4 << 10;
    if (lc >= 256 && lc < 768) vv = (tgt[b * 512 + (lc - 256)] << 10);
    TG[((lc & 7) << 7) + (lc >> 3)] = vv;
  }
  #pragma unroll
  for (int k = 0; k < 8; ++k) {
    const int a = lane + 64 * k;
    const float4 v = ((const float4*)pred)[b * 512 + a];
    const int base = ((a & 7) << 7) + 32 + (a >> 3);
    EPT[base]        = __expf(v.x);
    EPT[1024 + base] = __expf(v.y);
    EPT[2048 + base] = __expf(v.z);
    EPT[3072 + base] = __expf(v.w);
  }
  __syncthreads();

  int PE_[8], PO_[8];
  float A[8], R[8], D[8], SE[8], SO[8];
  #pragma unroll
  for (int s = 0; s < 8; ++s) {
    const int j = 8 * lane + s;
    const int pe1 = 255 + j, pe2 = 765 - j;
    PE_[s] = pe1 < pe2 ? pe1 : pe2;
    const int po2 = 764 - j;
    PO_[s] = pe1 < po2 ? pe1 : po2;
    A[s] = R[s] = D[s] = 0.0f;
    SE[s] = SO[s] = 0.0f;
  }
  float ac0 = 0.0f, ac1 = 0.0f, ac2 = 0.0f, ac3 = 0.0f;
  float one = 1.0f;
  int Etot = 0;
  const int lanem1 = (lane + 63) & 63;
  const int lanep1 = (lane + 1) & 63;
  const bool is0 = (lane == 0);
  const bool is63 = (lane == 63);

  int tgO[8], tgE0[8];
  float esE[8], esO[8];
  #pragma unroll
  for (int s = 0; s < 8; ++s) {
    tgE0[s] = TG[lane + (((s + 1) & 7) << 7) + ((s + 1) >> 3)];
    tgO[s]  = TG[lane + (((s + 2) & 7) << 7) + ((s + 2) >> 3)];
  }
  #pragma unroll
  for (int s = 0; s < 8; ++s) {
    esE[s] = EPT[tgE0[s] + (63 - lane) + ((7 - s) << 7)];
    esO[s] = EPT[tgO[s]  + (63 - lane) + ((7 - s) << 7)];
  }

  int esWb = 63 - lane;
  int tgWb = lane;
  float mcar = 0.0f;

  for (int b2 = 0; b2 < 64; ++b2) {
    #pragma unroll
    for (int t = 0; t < 8; ++t) {
      const int p = (b2 << 3) + t;
      const int pm1 = p - 1;

      int tgN[8];
      #pragma unroll
      for (int s = 0; s < 8; ++s)
        tgN[s] = TG[tgWb + (((s + 3 + t) & 7) << 7) + ((s + 3 + t) >> 3)];

      const float rc7 = A[7] * EGO + R[7] * EGE;
      float rcs = __shfl(rc7, lanem1, 64);
      float esEn[8];
      #pragma unroll
      for (int ss = 0; ss < 8; ++ss) {
        const int s = 7 - ss;
        float right;
        if (s == 0) right = is0 ? 0.0f : rcs;
        else        right = A[s - 1] * EGO + R[s - 1] * EGE;
        const float dn = (A[s] + R[s]) * EGO + D[s] * EGE;
        const bool val  = (p   <= PE_[s]);
        const bool valS = (pm1 <= PE_[s]);
        const float esg = val ? esE[s] : 0.0f;
        const float al  = esg * (SE[s] + one);
        const float pav = valS ? SE[s] : 0.0f;
        const float pa  = pav * esE[s];
        if ((s & 3) == 0) ac0 += pa; else if ((s & 3) == 1) ac1 += pa;
        else if ((s & 3) == 2) ac2 += pa; else ac3 += pa;
        const float s3 = al + right + dn;
        SE[s] = s3;
        A[s] = al; R[s] = right; D[s] = dn;
        esEn[s] = EPT[tgO[s] + esWb + (((7 - s + t + 1) & 7) << 7) + ((7 - s + t + 1) >> 3)];
      }

      const float uc0 = (A[0] + R[0]) * EGO + D[0] * EGE;
      float ucs = __shfl(uc0, lanep1, 64);
      #pragma unroll
      for (int s = 0; s < 8; ++s) {
        float dnv;
        if (s == 7) dnv = is63 ? 0.0f : ucs;
        else {
          dnv = (A[s + 1] + R[s + 1]) * EGO + D[s + 1] * EGE;
          if (s == 6) dnv = is63 ? 0.0f : dnv;
        }
        const float rt = A[s] * EGO + R[s] * EGE;
        const bool val  = (p   <= PO_[s]);
        const bool valS = (pm1 <= PO_[s]);
        const float esg = val ? esO[s] : 0.0f;
        const float al  = esg * (SO[s] + one);
        const float pav = valS ? SO[s] : 0.0f;
        const float pa  = pav * esO[s];
        if ((s & 3) == 0) ac0 += pa; else if ((s & 3) == 1) ac1 += pa;
        else if ((s & 3) == 2) ac2 += pa; else ac3 += pa;
        const float s3 = al + rt + dnv;
        SO[s] = s3;
        A[s] = al; R[s] = rt; D[s] = dnv;
      }

      float esOn[8];
      #pragma unroll
      for (int s = 0; s < 8; ++s)
        esOn[s] = EPT[tgN[s] + esWb + (((7 - s + t + 1) & 7) << 7) + ((7 - s + t + 1) >> 3)];

      #pragma unroll
      for (int s = 0; s < 8; ++s) { tgO[s] = tgN[s]; esE[s] = esEn[s]; esO[s] = esOn[s]; }
    }
    ++esWb; ++tgWb;

    if ((b2 & 1) == 0) {
      float mx = fmaxf(SE[0], SO[0]);
      #pragma unroll
      for (int s = 1; s < 8; ++s) mx = fmaxf(mx, fmaxf(SE[s], SO[s]));
      mx = fmaxf(mx, __shfl_xor(mx, 1, 64));
      mx = fmaxf(mx, __shfl_xor(mx, 2, 64));
      mx = fmaxf(mx, __shfl_xor(mx, 4, 64));
      mcar = mx;
    } else {
      float mx = mcar;
      mx = fmaxf(mx, __shfl_xor(mx, 8, 64));
      mx = fmaxf(mx, __shfl_xor(mx, 16, 64));
      mx = fmaxf(mx, __shfl_xor(mx, 32, 64));
      const int ex = (int)((__float_as_uint(mx) >> 23) & 0xff);
      const float sc = __uint_as_float((unsigned)(253 - ex) << 23);
      Etot += ex - 126;
      #pragma unroll
      for (int s = 0; s < 8; ++s) {
        A[s] *= sc; R[s] *= sc; D[s] *= sc; SE[s] *= sc; SO[s] *= sc;
      }
      ac0 *= sc; ac1 *= sc; ac2 *= sc; ac3 *= sc;
      one *= sc;
    }
  }

  float atot = (ac0 + ac1) + (ac2 + ac3);
  #pragma unroll
  for (int off = 1; off < 64; off <<= 1) atot += __shfl_xor(atot, off, 64);
  if (lane == 0) partials[b] = __logf(atot) + (float)Etot * 0.69314718055994531f;
}

__global__ void sw_reduce_kernel(const float* __restrict__ partials, float* __restrict__ out) {
  const int t = (int)threadIdx.x;
  float v = (t < 32) ? partials[t] : 0.0f;
  for (int off = 32; off; off >>= 1) v += __shfl_down(v, off, 64);
  if (t == 0) out[0] = -v * (1.0f / 32.0f);
}

extern "C" void kernel_launch(void* const* d_in, const int* in_sizes, int n_in,
                              void* d_out, int out_size, void* d_ws, size_t ws_size,
                              hipStream_t stream) {
  const float* pred = (const float*)d_in[0];   // (32, 512, 4) fp32
  const int*   tgt  = (const int*)d_in[1];     // (32, 512) int32
  float* partials = (float*)d_ws;              // 32 floats at offset 0
  float* out = (float*)d_out;                  // scalar

  // X needs 32*512*1024 halves = 32 MiB at offset 1024.
  if (ws_size >= (size_t)33555456ULL) {
    __half* X = (__half*)((char*)d_ws + 1024);
    sw_pre_kernel<<<16384, 512, 0, stream>>>(pred, tgt, X);
    sw_dp_fast<<<32, 64, 0, stream>>>(X, partials);
  } else {
    sw_dp_kernel<<<32, 64, 0, stream>>>(pred, tgt, partials);
  }
  sw_reduce_kernel<<<1, 64, 0, stream>>>(partials, out);
}

// Round 7
// 195.275 us; speedup vs baseline: 1.3601x; 1.3601x over previous
//
#include <hip/hip_runtime.h>

#define EGO 0.018315638888734179f   // exp(-4)
#define EGE 0.36787944117144233f    // exp(-1)

// =====================================================================
// Precompute diag-major gathered exp(scores), fp32, j-linear layout:
// X[((b*512+p)*2+half)*512 + j], half 0 = even-substep score, 1 = odd.
// Blocks of batch b land on XCD b%8 (same as DP block b) for L2 locality.
// =====================================================================
__global__ __launch_bounds__(512) void sw_pre_kernel(const float* __restrict__ pred,
                                                     const int* __restrict__ tgt,
                                                     float* __restrict__ X) {
  const int q = (int)blockIdx.x;
  const int b = (q & 7) | ((q >> 12) << 3);   // b%8 == q%8 -> XCD affinity
  const int p = (q >> 3) & 511;
  const int j = (int)threadIdx.x;
  const int a = 255 - j + p;
  const int c = p + j - 255;
  const bool av = (a >= 0) && (a < 512);
  float evn = 0.0f, odd = 0.0f;
  if (av && c >= 0 && c < 512)
    evn = __expf(pred[(((b << 9) + a) << 2) + tgt[(b << 9) + c]]);
  if (av && (c + 1) >= 0 && (c + 1) < 512)
    odd = __expf(pred[(((b << 9) + a) << 2) + tgt[(b << 9) + c + 1]]);
  float* base = X + (((size_t)((b << 9) | p)) << 10);
  base[j] = evn;
  base[512 + j] = odd;
}

// =====================================================================
// DP: 4 waves per batch (256 threads), 2 slots/lane: j = 128*w + 2*lane + s.
// Exp-domain DP in registers; cross-wave boundary values (1 float per
// boundary per substep) exchanged via LDS + RAW s_barrier (no vmcnt drain,
// so the 4-deep X prefetch stays in flight across barriers).
// RESCALE FIX vs R6: after scaling registers, the XRl boundary value is
// republished (scaled) + one extra barrier — otherwise the LDS copy goes
// stale by the cumulative scale factor and overflows to inf/NaN.
// =====================================================================
__global__ __launch_bounds__(256) void sw_dp_fast(const float* __restrict__ X,
                                                  float* __restrict__ partials) {
  __shared__ float XRl[4], XDl[4], MXl[4], SUMl[4];
  const int tid = (int)threadIdx.x;
  const int w = tid >> 6, lane = tid & 63;
  const int b = (int)blockIdx.x;
  const float* Xb = X + ((size_t)b << 19);   // 512*1024 floats per batch

  if (tid < 4) { XRl[tid] = 0.0f; XDl[tid] = 0.0f; }
  __syncthreads();

  const int j0 = 128 * w + 2 * lane;
  int PE0, PE1, PO0, PO1;
  { const int j = j0;     PE0 = min(255 + j, 765 - j); PO0 = min(255 + j, 764 - j); }
  { const int j = j0 + 1; PE1 = min(255 + j, 765 - j); PO1 = min(255 + j, 764 - j); }
  float U0=0,U1=0,D0=0,D1=0,SE0=0,SE1=0,SEp0=0,SEp1=0,SO0=0,SO1=0,SOp0=0,SOp1=0,RC0=0,RC1=0;
  float acc0 = 0.0f, acc1 = 0.0f;
  float one = 1.0f;      // 2^-Etot
  int Etot = 0;
  const int lanem1 = (lane + 63) & 63;
  const int lanep1 = (lane + 1) & 63;
  const bool is0 = (lane == 0), is63 = (lane == 63);
  const bool isPh = (w == 3) && is63;     // slot 511 (phantom)
  const bool leftEdge = (w == 0);
  const bool rightEdge = (w == 3);

  float2 evb[4], odb[4];

#define LOADP(par, p) do {                                                    \
    const float2* q_ = (const float2*)(Xb + ((size_t)(p) << 10));             \
    evb[par] = q_[64 * w + lane];                                             \
    odb[par] = q_[256 + 64 * w + lane];                                       \
  } while (0)

// Raw barrier: NO vmcnt drain (prefetch survives); lgkmcnt(0) retires this
// wave's LDS ops (both edge ds_writes and prior ds_reads) before the barrier;
// clobbers pin LDS op ordering around the barrier.
#define SYNC() do {                                                           \
    asm volatile("s_waitcnt lgkmcnt(0)" ::: "memory");                        \
    __builtin_amdgcn_s_barrier();                                             \
    asm volatile("" ::: "memory");                                            \
  } while (0)

#define ITER(par, p) do {                                                     \
    float xr_ = XRl[(w + 3) & 3];                                             \
    const float xr0_ = leftEdge ? 0.0f : xr_;                                 \
    float DCl0_, DCl1_, RCe0_, RCe1_;                                         \
    { /* EVENS (d=2p): s=1 first; shuffled rcS consumed last (s=0) */         \
      const float rcS = __shfl(RC1, lanem1, 64);                              \
      { /* s=1 */                                                             \
        const float right = RC0;                                              \
        const float dn = U1 * EGO + D1 * EGE;                                 \
        const bool v = ((p) <= PE1);                                          \
        const float raw = evb[par].y;                                         \
        acc1 += SEp1 * raw;                                                   \
        const float esg = v ? raw : 0.0f;                                     \
        const float al = esg * (SE1 + one);                                   \
        const float Un = al + right;                                          \
        const float s3 = Un + dn;                                             \
        SE1 = s3; SEp1 = v ? s3 : 0.0f;                                       \
        U1 = Un; D1 = dn;                                                     \
        float dc = Un * EGO + dn * EGE;                                       \
        if (isPh) dc = 0.0f;                                                  \
        DCl1_ = dc; RCe1_ = al * EGO + right * EGE;                           \
      }                                                                       \
      { /* s=0 */                                                             \
        const float right = is0 ? xr0_ : rcS;                                 \
        const float dn = U0 * EGO + D0 * EGE;                                 \
        const bool v = ((p) <= PE0);                                          \
        const float raw = evb[par].x;                                         \
        acc0 += SEp0 * raw;                                                   \
        const float esg = v ? raw : 0.0f;                                     \
        const float al = esg * (SE0 + one);                                   \
        const float Un = al + right;                                          \
        const float s3 = Un + dn;                                             \
        SE0 = s3; SEp0 = v ? s3 : 0.0f;                                       \
        U0 = Un; D0 = dn;                                                     \
        DCl0_ = Un * EGO + dn * EGE; RCe0_ = al * EGO + right * EGE;          \
      }                                                                       \
    }                                                                         \
    if (is0) XDl[w] = DCl0_;                                                  \
    SYNC();                                                                   \
    float xd_ = XDl[(w + 1) & 3];                                             \
    const float xd3_ = rightEdge ? 0.0f : xd_;                                \
    { /* ODDS (d=2p+1): s=0 first; shuffled dcS consumed last (s=1) */        \
      const float dcS = __shfl(DCl0_, lanep1, 64);                            \
      { /* s=0 */                                                             \
        const float dnv = DCl1_;                                              \
        const float right = RCe0_;                                            \
        const bool v = ((p) <= PO0);                                          \
        const float raw = odb[par].x;                                         \
        acc0 += SOp0 * raw;                                                   \
        const float esg = v ? raw : 0.0f;                                     \
        const float al = esg * (SO0 + one);                                   \
        const float Un = al + right;                                          \
        const float s3 = Un + dnv;                                            \
        SO0 = s3; SOp0 = v ? s3 : 0.0f;                                       \
        U0 = Un; D0 = dnv;                                                    \
        RC0 = al * EGO + right * EGE;                                         \
      }                                                                       \
      { /* s=1 */                                                             \
        const float dnv = is63 ? xd3_ : dcS;                                  \
        const float right = RCe1_;                                            \
        const bool v = ((p) <= PO1);                                          \
        const float raw = odb[par].y;                                         \
        acc1 += SOp1 * raw;                                                   \
        const float esg = v ? raw : 0.0f;                                     \
        const float al = esg * (SO1 + one);                                   \
        const float Un = al + right;                                          \
        const float s3 = Un + dnv;                                            \
        SO1 = s3; SOp1 = v ? s3 : 0.0f;                                       \
        U1 = Un; D1 = dnv;                                                    \
        RC1 = al * EGO + right * EGE;                                         \
      }                                                                       \
    }                                                                         \
    if (is63) XRl[w] = RC1;                                                   \
    SYNC();                                                                   \
  } while (0)

  LOADP(0, 0); LOADP(1, 1); LOADP(2, 2); LOADP(3, 3);

  for (int qq = 0; qq < 127; ++qq) {
    const int p0 = qq << 2;
    ITER(0, p0);     LOADP(0, p0 + 4);
    ITER(1, p0 + 1); LOADP(1, p0 + 5);
    ITER(2, p0 + 2); LOADP(2, p0 + 6);
    ITER(3, p0 + 3); LOADP(3, p0 + 7);
    if ((qq & 3) == 3) {   // joint rescale every 16 p (wave-uniform branch)
      float mx = fmaxf(fmaxf(SE0, SE1), fmaxf(SO0, SO1));
      #pragma unroll
      for (int off = 1; off < 64; off <<= 1) mx = fmaxf(mx, __shfl_xor(mx, off, 64));
      if (is0) MXl[w] = mx;
      SYNC();
      mx = fmaxf(fmaxf(MXl[0], MXl[1]), fmaxf(MXl[2], MXl[3]));
      const int ex = (int)((__float_as_uint(mx) >> 23) & 0xff);
      const float sc = __uint_as_float((unsigned)(253 - ex) << 23);  // 2^(126-ex)
      Etot += ex - 126;
      U0*=sc; U1*=sc; D0*=sc; D1*=sc; RC0*=sc; RC1*=sc;
      SE0*=sc; SE1*=sc; SEp0*=sc; SEp1*=sc; SO0*=sc; SO1*=sc; SOp0*=sc; SOp1*=sc;
      acc0*=sc; acc1*=sc; one*=sc;
      // FIX: republish the rescaled boundary so LDS copy matches register scale
      if (is63) XRl[w] = RC1;
      SYNC();
    }
  }
  // tail: p = 508, 509, 510 (no further loads)
  ITER(0, 508); ITER(1, 509); ITER(2, 510);
  // epilogue p = 511: pa-only, consumes buffer 3
  acc0 += SEp0 * evb[3].x + SOp0 * odb[3].x;
  acc1 += SEp1 * evb[3].y + SOp1 * odb[3].y;

  float atot = acc0 + acc1;
  #pragma unroll
  for (int off = 1; off < 64; off <<= 1) atot += __shfl_xor(atot, off, 64);
  if (is0) SUMl[w] = atot;
  __syncthreads();
  if (tid == 0) {
    const float a = (SUMl[0] + SUMl[1]) + (SUMl[2] + SUMl[3]);
    partials[b] = __logf(a) + (float)Etot * 0.69314718055994531f;
  }

#undef LOADP
#undef SYNC
#undef ITER
}

// =====================================================================
// Fallback (R3, validated absmax 0.0): used when ws_size is too small.
// =====================================================================
__global__ __launch_bounds__(64) void sw_dp_kernel(const float* __restrict__ pred,
                                                   const int* __restrict__ tgt,
                                                   float* __restrict__ partials) {
  __shared__ float EPT[5120];
  __shared__ int   TG[1024];

  const int lane = (int)threadIdx.x;
  const int b = (int)blockIdx.x;

  #pragma unroll
  for (int k = 0; k < 80; ++k) EPT[lane + 64 * k] = 0.0f;
  #pragma unroll
  for (int k = 0; k < 16; ++k) {
    const int lc = lane + 64 * k;
    int vv = 4 << 10;
    if (lc >= 256 && lc < 768) vv = (tgt[b * 512 + (lc - 256)] << 10);
    TG[((lc & 7) << 7) + (lc >> 3)] = vv;
  }
  #pragma unroll
  for (int k = 0; k < 8; ++k) {
    const int a = lane + 64 * k;
    const float4 v = ((const float4*)pred)[b * 512 + a];
    const int base = ((a & 7) << 7) + 32 + (a >> 3);
    EPT[base]        = __expf(v.x);
    EPT[1024 + base] = __expf(v.y);
    EPT[2048 + base] = __expf(v.z);
    EPT[3072 + base] = __expf(v.w);
  }
  __syncthreads();

  int PE_[8], PO_[8];
  float A[8], R[8], D[8], SE[8], SO[8];
  #pragma unroll
  for (int s = 0; s < 8; ++s) {
    const int j = 8 * lane + s;
    const int pe1 = 255 + j, pe2 = 765 - j;
    PE_[s] = pe1 < pe2 ? pe1 : pe2;
    const int po2 = 764 - j;
    PO_[s] = pe1 < po2 ? pe1 : po2;
    A[s] = R[s] = D[s] = 0.0f;
    SE[s] = SO[s] = 0.0f;
  }
  float ac0 = 0.0f, ac1 = 0.0f, ac2 = 0.0f, ac3 = 0.0f;
  float one = 1.0f;
  int Etot = 0;
  const int lanem1 = (lane + 63) & 63;
  const int lanep1 = (lane + 1) & 63;
  const bool is0 = (lane == 0);
  const bool is63 = (lane == 63);

  int tgO[8], tgE0[8];
  float esE[8], esO[8];
  #pragma unroll
  for (int s = 0; s < 8; ++s) {
    tgE0[s] = TG[lane + (((s + 1) & 7) << 7) + ((s + 1) >> 3)];
    tgO[s]  = TG[lane + (((s + 2) & 7) << 7) + ((s + 2) >> 3)];
  }
  #pragma unroll
  for (int s = 0; s < 8; ++s) {
    esE[s] = EPT[tgE0[s] + (63 - lane) + ((7 - s) << 7)];
    esO[s] = EPT[tgO[s]  + (63 - lane) + ((7 - s) << 7)];
  }

  int esWb = 63 - lane;
  int tgWb = lane;
  float mcar = 0.0f;

  for (int b2 = 0; b2 < 64; ++b2) {
    #pragma unroll
    for (int t = 0; t < 8; ++t) {
      const int p = (b2 << 3) + t;
      const int pm1 = p - 1;

      int tgN[8];
      #pragma unroll
      for (int s = 0; s < 8; ++s)
        tgN[s] = TG[tgWb + (((s + 3 + t) & 7) << 7) + ((s + 3 + t) >> 3)];

      const float rc7 = A[7] * EGO + R[7] * EGE;
      float rcs = __shfl(rc7, lanem1, 64);
      float esEn[8];
      #pragma unroll
      for (int ss = 0; ss < 8; ++ss) {
        const int s = 7 - ss;
        float right;
        if (s == 0) right = is0 ? 0.0f : rcs;
        else        right = A[s - 1] * EGO + R[s - 1] * EGE;
        const float dn = (A[s] + R[s]) * EGO + D[s] * EGE;
        const bool val  = (p   <= PE_[s]);
        const bool valS = (pm1 <= PE_[s]);
        const float esg = val ? esE[s] : 0.0f;
        const float al  = esg * (SE[s] + one);
        const float pav = valS ? SE[s] : 0.0f;
        const float pa  = pav * esE[s];
        if ((s & 3) == 0) ac0 += pa; else if ((s & 3) == 1) ac1 += pa;
        else if ((s & 3) == 2) ac2 += pa; else ac3 += pa;
        const float s3 = al + right + dn;
        SE[s] = s3;
        A[s] = al; R[s] = right; D[s] = dn;
        esEn[s] = EPT[tgO[s] + esWb + (((7 - s + t + 1) & 7) << 7) + ((7 - s + t + 1) >> 3)];
      }

      const float uc0 = (A[0] + R[0]) * EGO + D[0] * EGE;
      float ucs = __shfl(uc0, lanep1, 64);
      #pragma unroll
      for (int s = 0; s < 8; ++s) {
        float dnv;
        if (s == 7) dnv = is63 ? 0.0f : ucs;
        else {
          dnv = (A[s + 1] + R[s + 1]) * EGO + D[s + 1] * EGE;
          if (s == 6) dnv = is63 ? 0.0f : dnv;
        }
        const float rt = A[s] * EGO + R[s] * EGE;
        const bool val  = (p   <= PO_[s]);
        const bool valS = (pm1 <= PO_[s]);
        const float esg = val ? esO[s] : 0.0f;
        const float al  = esg * (SO[s] + one);
        const float pav = valS ? SO[s] : 0.0f;
        const float pa  = pav * esO[s];
        if ((s & 3) == 0) ac0 += pa; else if ((s & 3) == 1) ac1 += pa;
        else if ((s & 3) == 2) ac2 += pa; else ac3 += pa;
        const float s3 = al + rt + dnv;
        SO[s] = s3;
        A[s] = al; R[s] = rt; D[s] = dnv;
      }

      float esOn[8];
      #pragma unroll
      for (int s = 0; s < 8; ++s)
        esOn[s] = EPT[tgN[s] + esWb + (((7 - s + t + 1) & 7) << 7) + ((7 - s + t + 1) >> 3)];

      #pragma unroll
      for (int s = 0; s < 8; ++s) { tgO[s] = tgN[s]; esE[s] = esEn[s]; esO[s] = esOn[s]; }
    }
    ++esWb; ++tgWb;

    if ((b2 & 1) == 0) {
      float mx = fmaxf(SE[0], SO[0]);
      #pragma unroll
      for (int s = 1; s < 8; ++s) mx = fmaxf(mx, fmaxf(SE[s], SO[s]));
      mx = fmaxf(mx, __shfl_xor(mx, 1, 64));
      mx = fmaxf(mx, __shfl_xor(mx, 2, 64));
      mx = fmaxf(mx, __shfl_xor(mx, 4, 64));
      mcar = mx;
    } else {
      float mx = mcar;
      mx = fmaxf(mx, __shfl_xor(mx, 8, 64));
      mx = fmaxf(mx, __shfl_xor(mx, 16, 64));
      mx = fmaxf(mx, __shfl_xor(mx, 32, 64));
      const int ex = (int)((__float_as_uint(mx) >> 23) & 0xff);
      const float sc = __uint_as_float((unsigned)(253 - ex) << 23);
      Etot += ex - 126;
      #pragma unroll
      for (int s = 0; s < 8; ++s) {
        A[s] *= sc; R[s] *= sc; D[s] *= sc; SE[s] *= sc; SO[s] *= sc;
      }
      ac0 *= sc; ac1 *= sc; ac2 *= sc; ac3 *= sc;
      one *= sc;
    }
  }

  float atot = (ac0 + ac1) + (ac2 + ac3);
  #pragma unroll
  for (int off = 1; off < 64; off <<= 1) atot += __shfl_xor(atot, off, 64);
  if (lane == 0) partials[b] = __logf(atot) + (float)Etot * 0.69314718055994531f;
}

__global__ void sw_reduce_kernel(const float* __restrict__ partials, float* __restrict__ out) {
  const int t = (int)threadIdx.x;
  float v = (t < 32) ? partials[t] : 0.0f;
  for (int off = 32; off; off >>= 1) v += __shfl_down(v, off, 64);
  if (t == 0) out[0] = -v * (1.0f / 32.0f);
}

extern "C" void kernel_launch(void* const* d_in, const int* in_sizes, int n_in,
                              void* d_out, int out_size, void* d_ws, size_t ws_size,
                              hipStream_t stream) {
  const float* pred = (const float*)d_in[0];   // (32, 512, 4) fp32
  const int*   tgt  = (const int*)d_in[1];     // (32, 512) int32
  float* partials = (float*)d_ws;              // 32 floats at offset 0
  float* out = (float*)d_out;                  // scalar

  // X needs 32*512*1024 floats = 64 MiB at offset 1024 (validated fits in R4).
  if (ws_size >= (size_t)67109888ULL) {
    float* X = (float*)((char*)d_ws + 1024);
    sw_pre_kernel<<<16384, 512, 0, stream>>>(pred, tgt, X);
    sw_dp_fast<<<32, 256, 0, stream>>>(X, partials);
  } else {
    sw_dp_kernel<<<32, 64, 0, stream>>>(pred, tgt, partials);
  }
  sw_reduce_kernel<<<1, 64, 0, stream>>>(partials, out);
}

// Round 8
// 171.410 us; speedup vs baseline: 1.5495x; 1.1392x over previous
//
#include <hip/hip_runtime.h>

#define EGO 0.018315638888734179f   // exp(-4)
#define EGE 0.36787944117144233f    // exp(-1)

__device__ __forceinline__ float escale(int k) {   // 2^k, clamped to normal range
  k = k < -126 ? -126 : (k > 127 ? 127 : k);
  return __uint_as_float((unsigned)(k + 127) << 23);
}

// =====================================================================
// Precompute diag-major gathered exp(scores), fp32:
// X[((b*512+p)*2+half)*512 + j]. Batch b's blocks land on XCD b%8.
// =====================================================================
__global__ __launch_bounds__(512) void sw_pre_kernel(const float* __restrict__ pred,
                                                     const int* __restrict__ tgt,
                                                     float* __restrict__ X) {
  const int q = (int)blockIdx.x;
  const int b = (q & 7) | ((q >> 12) << 3);
  const int p = (q >> 3) & 511;
  const int j = (int)threadIdx.x;
  const int a = 255 - j + p;
  const int c = p + j - 255;
  const bool av = (a >= 0) && (a < 512);
  float evn = 0.0f, odd = 0.0f;
  if (av && c >= 0 && c < 512)
    evn = __expf(pred[(((b << 9) + a) << 2) + tgt[(b << 9) + c]]);
  if (av && (c + 1) >= 0 && (c + 1) < 512)
    odd = __expf(pred[(((b << 9) + a) << 2) + tgt[(b << 9) + c + 1]]);
  float* base = X + (((size_t)((b << 9) | p)) << 10);
  base[j] = evn;
  base[512 + j] = odd;
}

// =====================================================================
// DP with halo (overlapped tiling): 4 waves/batch, 3 slots/lane.
// Wave w computes j in [128w-32, 128w+160) (192 slots), OWNS [128w,128w+128).
// 32 iters run barrier-free (halo absorbs the dependency cone); every 32
// iters a refresh re-copies boundary state owner->halo via LDS (2 barriers).
// Per-wave solo rescale every 16 iters; scales reconciled at refresh.
// =====================================================================
__global__ __launch_bounds__(256) void sw_dp_fast(const float* __restrict__ X,
                                                  float* __restrict__ partials) {
  __shared__ float SLDS[4096];            // [512 slots][8 floats]
  __shared__ float MXl[4], SUMl[4];
  __shared__ int   ETl[4], ETf[4];

  const int tid = (int)threadIdx.x;
  const int w = tid >> 6, lane = tid & 63;
  const int b = (int)blockIdx.x;
  const float* Xb = X + ((size_t)b << 19);
  const int Wbase = 128 * w - 32;
  const int jld = Wbase + 3 * lane;
  const int lanem1 = (lane + 63) & 63;
  const int lanep1 = (lane + 1) & 63;

  // ---- per-slot static config ----
  int jj[3], PEes[3], POes[3], PEac[3], POac[3];
  bool isPh[3], wrS[3], rdh[3], phh[3], owS[3];
  #pragma unroll
  for (int s = 0; s < 3; ++s) {
    const int j = jld + s;
    jj[s] = j;
    const bool vj = (j >= 0) && (j < 512);
    const int pe = (255 + j < 765 - j) ? 255 + j : 765 - j;
    const int po = (255 + j < 764 - j) ? 255 + j : 764 - j;
    PEes[s] = vj ? pe : -1;
    POes[s] = vj ? po : -1;
    const bool ow = (j >= 128 * w) && (j < 128 * w + 128);
    owS[s] = ow;
    PEac[s] = ow ? pe : -1;
    POac[s] = ow ? po : -1;
    isPh[s] = (j == 511);
    const int idx = 3 * lane + s;
    wrS[s] = (idx >= 32 && idx < 64) || (idx >= 128 && idx < 160);
    const bool halo = (idx < 32) || (idx >= 160);
    rdh[s] = halo && vj;
    phh[s] = halo && !vj;
  }

  float U[3], Dd[3], RC[3], SE[3], SEp[3], SO[3], SOp[3], DCt[3], RCe[3];
  float acc[3];
  #pragma unroll
  for (int s = 0; s < 3; ++s) {
    U[s] = Dd[s] = RC[s] = SE[s] = SEp[s] = SO[s] = SOp[s] = 0.0f;
    acc[s] = 0.0f;
  }
  float one = 1.0f;
  int EtotW = 0;

  float3 evb[4], odb[4];

#define LOADP(par, p) do {                                                    \
    const float* row_ = Xb + (((size_t)(p)) << 10);                           \
    evb[par] = *(const float3*)(row_ + jld);                                  \
    odb[par] = *(const float3*)(row_ + 512 + jld);                            \
  } while (0)

#define SYNC() do {                                                           \
    asm volatile("s_waitcnt lgkmcnt(0)" ::: "memory");                        \
    __builtin_amdgcn_s_barrier();                                             \
    asm volatile("" ::: "memory");                                            \
  } while (0)

#define EVENS(p, e0, e1, e2) do {                                             \
    const float rcS_ = __shfl(RC[2], lanem1, 64);                             \
    const float raws_[3] = {e0, e1, e2};                                      \
    _Pragma("unroll")                                                         \
    for (int ss = 2; ss >= 0; --ss) {                                         \
      const float raw = raws_[ss];                                            \
      const float right = (ss == 0) ? rcS_ : RC[ss - 1];                      \
      const float dn = U[ss] * EGO + Dd[ss] * EGE;                            \
      acc[ss] += SEp[ss] * raw;                                               \
      const float esg = ((p) <= PEes[ss]) ? raw : 0.0f;                       \
      const float al = esg * (SE[ss] + one);                                  \
      const float Un = al + right;                                            \
      const float s3 = Un + dn;                                               \
      SE[ss] = s3; SEp[ss] = ((p) <= PEac[ss]) ? s3 : 0.0f;                   \
      U[ss] = Un; Dd[ss] = dn;                                                \
      float dc = Un * EGO + dn * EGE;                                         \
      dc = isPh[ss] ? 0.0f : dc;                                              \
      DCt[ss] = dc; RCe[ss] = al * EGO + right * EGE;                         \
    }                                                                         \
  } while (0)

#define ODDS(p, o0, o1, o2) do {                                              \
    const float dcS_ = __shfl(DCt[0], lanep1, 64);                            \
    const float raws_[3] = {o0, o1, o2};                                      \
    _Pragma("unroll")                                                         \
    for (int ss = 0; ss < 3; ++ss) {                                          \
      const float raw = raws_[ss];                                            \
      const float dnv = (ss == 2) ? dcS_ : DCt[ss + 1];                       \
      const float right = RCe[ss];                                            \
      acc[ss] += SOp[ss] * raw;                                               \
      const float esg = ((p) <= POes[ss]) ? raw : 0.0f;                       \
      const float al = esg * (SO[ss] + one);                                  \
      const float Un = al + right;                                            \
      const float s3 = Un + dnv;                                              \
      SO[ss] = s3; SOp[ss] = ((p) <= POac[ss]) ? s3 : 0.0f;                   \
      U[ss] = Un; Dd[ss] = dnv;                                               \
      RC[ss] = al * EGO + right * EGE;                                        \
    }                                                                         \
  } while (0)

#define ITER(par, p) do {                                                     \
    EVENS(p, evb[par].x, evb[par].y, evb[par].z);                             \
    ODDS(p, odb[par].x, odb[par].y, odb[par].z);                              \
  } while (0)

#define SOLO() do {                                                           \
    float mxl = 0.0f;                                                         \
    _Pragma("unroll")                                                         \
    for (int s = 0; s < 3; ++s) mxl = fmaxf(mxl, fmaxf(SE[s], SO[s]));        \
    _Pragma("unroll")                                                         \
    for (int off = 1; off < 64; off <<= 1) mxl = fmaxf(mxl, __shfl_xor(mxl, off, 64)); \
    const int ex = (int)((__float_as_uint(mxl) >> 23) & 0xff);                \
    if (ex > 0) {                                                             \
      const float sc = __uint_as_float((unsigned)(253 - ex) << 23);           \
      EtotW += ex - 126;                                                      \
      _Pragma("unroll")                                                       \
      for (int s = 0; s < 3; ++s) {                                           \
        U[s] *= sc; Dd[s] *= sc; RC[s] *= sc; SE[s] *= sc; SO[s] *= sc;       \
        SEp[s] *= sc; SOp[s] *= sc; acc[s] *= sc;                             \
      }                                                                       \
      one *= sc;                                                              \
    }                                                                         \
  } while (0)

#define REFRESH() do {                                                        \
    float mxl = 0.0f;                                                         \
    _Pragma("unroll")                                                         \
    for (int s = 0; s < 3; ++s) {                                             \
      float t_ = fmaxf(SE[s], SO[s]);                                         \
      mxl = fmaxf(mxl, owS[s] ? t_ : 0.0f);                                   \
    }                                                                         \
    _Pragma("unroll")                                                         \
    for (int off = 1; off < 64; off <<= 1) mxl = fmaxf(mxl, __shfl_xor(mxl, off, 64)); \
    if (lane == 0) { MXl[w] = mxl; ETl[w] = EtotW; }                          \
    _Pragma("unroll")                                                         \
    for (int s = 0; s < 3; ++s) if (wrS[s]) {                                 \
      float4 v4_; v4_.x = U[s]; v4_.y = Dd[s]; v4_.z = RC[s]; v4_.w = SE[s];  \
      *(float4*)(&SLDS[jj[s] * 8]) = v4_;                                     \
      SLDS[jj[s] * 8 + 4] = SO[s];                                            \
    }                                                                         \
    SYNC();                                                                   \
    int ets_[4]; float mxs_[4];                                               \
    _Pragma("unroll")                                                         \
    for (int q2 = 0; q2 < 4; ++q2) { mxs_[q2] = MXl[q2]; ets_[q2] = ETl[q2]; }\
    int tn_ = -2147483647;                                                    \
    _Pragma("unroll")                                                         \
    for (int q2 = 0; q2 < 4; ++q2) {                                          \
      if (mxs_[q2] > 0.0f) {                                                  \
        const int t2_ = ets_[q2] + (int)((__float_as_uint(mxs_[q2]) >> 23) & 0xff) - 126; \
        if (t2_ > tn_) tn_ = t2_;                                             \
      }                                                                       \
    }                                                                         \
    if (tn_ == -2147483647) tn_ = EtotW;   /* all-zero safeguard */           \
    { const int dd_ = EtotW - tn_;                                            \
      const float f1_ = escale(dd_ - dd_ / 2), f2_ = escale(dd_ / 2);         \
      _Pragma("unroll")                                                       \
      for (int s = 0; s < 3; ++s) {                                           \
        U[s] = U[s] * f1_ * f2_; Dd[s] = Dd[s] * f1_ * f2_;                   \
        RC[s] = RC[s] * f1_ * f2_; SE[s] = SE[s] * f1_ * f2_;                 \
        SO[s] = SO[s] * f1_ * f2_; SEp[s] = SEp[s] * f1_ * f2_;               \
        SOp[s] = SOp[s] * f1_ * f2_; acc[s] = acc[s] * f1_ * f2_;             \
      }                                                                       \
      one = one * f1_ * f2_; EtotW = tn_;                                     \
    }                                                                         \
    _Pragma("unroll")                                                         \
    for (int s = 0; s < 3; ++s) {                                             \
      if (rdh[s]) {                                                           \
        const int oww_ = (3 * lane + s < 32) ? (w - 1) : (w + 1);             \
        const int dd2_ = ets_[oww_] - EtotW;                                  \
        const float g1_ = escale(dd2_ - dd2_ / 2), g2_ = escale(dd2_ / 2);    \
        const float4 v4_ = *(const float4*)(&SLDS[jj[s] * 8]);                \
        U[s] = v4_.x * g1_ * g2_; Dd[s] = v4_.y * g1_ * g2_;                  \
        RC[s] = v4_.z * g1_ * g2_; SE[s] = v4_.w * g1_ * g2_;                 \
        SO[s] = SLDS[jj[s] * 8 + 4] * g1_ * g2_;                              \
        SEp[s] = 0.0f; SOp[s] = 0.0f;                                         \
      } else if (phh[s]) {                                                    \
        U[s] = 0.0f; Dd[s] = 0.0f; RC[s] = 0.0f; SE[s] = 0.0f; SO[s] = 0.0f;  \
        SEp[s] = 0.0f; SOp[s] = 0.0f;                                         \
      }                                                                       \
    }                                                                         \
    SYNC();                                                                   \
  } while (0)

  LOADP(0, 0); LOADP(1, 1); LOADP(2, 2); LOADP(3, 3);

  for (int qq = 0; qq < 127; ++qq) {
    const int p0 = qq << 2;
    ITER(0, p0);     LOADP(0, p0 + 4);
    ITER(1, p0 + 1); LOADP(1, p0 + 5);
    ITER(2, p0 + 2); LOADP(2, p0 + 6);
    ITER(3, p0 + 3); LOADP(3, p0 + 7);
    const int ph = qq & 7;
    if (ph == 3) SOLO();
    else if (ph == 7) REFRESH();
  }
  // tail: p = 508, 509, 510
  ITER(0, 508); ITER(1, 509); ITER(2, 510);
  // epilogue p = 511: pending pa terms consume buffer 3
  acc[0] += SEp[0] * evb[3].x + SOp[0] * odb[3].x;
  acc[1] += SEp[1] * evb[3].y + SOp[1] * odb[3].y;
  acc[2] += SEp[2] * evb[3].z + SOp[2] * odb[3].z;

  float atot = acc[0] + acc[1] + acc[2];
  #pragma unroll
  for (int off = 1; off < 64; off <<= 1) atot += __shfl_xor(atot, off, 64);
  if (lane == 0) { SUMl[w] = atot; ETf[w] = EtotW; }
  __syncthreads();
  if (tid == 0) {
    int M = ETf[0];
    for (int q2 = 1; q2 < 4; ++q2) if (ETf[q2] > M) M = ETf[q2];
    float T = 0.0f;
    for (int q2 = 0; q2 < 4; ++q2) T += SUMl[q2] * escale(ETf[q2] - M);
    partials[b] = __logf(T) + (float)M * 0.69314718055994531f;
  }

#undef LOADP
#undef SYNC
#undef EVENS
#undef ODDS
#undef ITER
#undef SOLO
#undef REFRESH
}

// =====================================================================
// Fallback (R3, validated absmax 0.0): used when ws_size is too small.
// =====================================================================
__global__ __launch_bounds__(64) void sw_dp_kernel(const float* __restrict__ pred,
                                                   const int* __restrict__ tgt,
                                                   float* __restrict__ partials) {
  __shared__ float EPT[5120];
  __shared__ int   TG[1024];

  const int lane = (int)threadIdx.x;
  const int b = (int)blockIdx.x;

  #pragma unroll
  for (int k = 0; k < 80; ++k) EPT[lane + 64 * k] = 0.0f;
  #pragma unroll
  for (int k = 0; k < 16; ++k) {
    const int lc = lane + 64 * k;
    int vv = 4 << 10;
    if (lc >= 256 && lc < 768) vv = (tgt[b * 512 + (lc - 256)] << 10);
    TG[((lc & 7) << 7) + (lc >> 3)] = vv;
  }
  #pragma unroll
  for (int k = 0; k < 8; ++k) {
    const int a = lane + 64 * k;
    const float4 v = ((const float4*)pred)[b * 512 + a];
    const int base = ((a & 7) << 7) + 32 + (a >> 3);
    EPT[base]        = __expf(v.x);
    EPT[1024 + base] = __expf(v.y);
    EPT[2048 + base] = __expf(v.z);
    EPT[3072 + base] = __expf(v.w);
  }
  __syncthreads();

  int PE_[8], PO_[8];
  float A[8], R[8], D[8], SE[8], SO[8];
  #pragma unroll
  for (int s = 0; s < 8; ++s) {
    const int j = 8 * lane + s;
    const int pe1 = 255 + j, pe2 = 765 - j;
    PE_[s] = pe1 < pe2 ? pe1 : pe2;
    const int po2 = 764 - j;
    PO_[s] = pe1 < po2 ? pe1 : po2;
    A[s] = R[s] = D[s] = 0.0f;
    SE[s] = SO[s] = 0.0f;
  }
  float ac0 = 0.0f, ac1 = 0.0f, ac2 = 0.0f, ac3 = 0.0f;
  float one = 1.0f;
  int Etot = 0;
  const int lanem1 = (lane + 63) & 63;
  const int lanep1 = (lane + 1) & 63;
  const bool is0 = (lane == 0);
  const bool is63 = (lane == 63);

  int tgO[8], tgE0[8];
  float esE[8], esO[8];
  #pragma unroll
  for (int s = 0; s < 8; ++s) {
    tgE0[s] = TG[lane + (((s + 1) & 7) << 7) + ((s + 1) >> 3)];
    tgO[s]  = TG[lane + (((s + 2) & 7) << 7) + ((s + 2) >> 3)];
  }
  #pragma unroll
  for (int s = 0; s < 8; ++s) {
    esE[s] = EPT[tgE0[s] + (63 - lane) + ((7 - s) << 7)];
    esO[s] = EPT[tgO[s]  + (63 - lane) + ((7 - s) << 7)];
  }

  int esWb = 63 - lane;
  int tgWb = lane;
  float mcar = 0.0f;

  for (int b2 = 0; b2 < 64; ++b2) {
    #pragma unroll
    for (int t = 0; t < 8; ++t) {
      const int p = (b2 << 3) + t;
      const int pm1 = p - 1;

      int tgN[8];
      #pragma unroll
      for (int s = 0; s < 8; ++s)
        tgN[s] = TG[tgWb + (((s + 3 + t) & 7) << 7) + ((s + 3 + t) >> 3)];

      const float rc7 = A[7] * EGO + R[7] * EGE;
      float rcs = __shfl(rc7, lanem1, 64);
      float esEn[8];
      #pragma unroll
      for (int ss = 0; ss < 8; ++ss) {
        const int s = 7 - ss;
        float right;
        if (s == 0) right = is0 ? 0.0f : rcs;
        else        right = A[s - 1] * EGO + R[s - 1] * EGE;
        const float dn = (A[s] + R[s]) * EGO + D[s] * EGE;
        const bool val  = (p   <= PE_[s]);
        const bool valS = (pm1 <= PE_[s]);
        const float esg = val ? esE[s] : 0.0f;
        const float al  = esg * (SE[s] + one);
        const float pav = valS ? SE[s] : 0.0f;
        const float pa  = pav * esE[s];
        if ((s & 3) == 0) ac0 += pa; else if ((s & 3) == 1) ac1 += pa;
        else if ((s & 3) == 2) ac2 += pa; else ac3 += pa;
        const float s3 = al + right + dn;
        SE[s] = s3;
        A[s] = al; R[s] = right; D[s] = dn;
        esEn[s] = EPT[tgO[s] + esWb + (((7 - s + t + 1) & 7) << 7) + ((7 - s + t + 1) >> 3)];
      }

      const float uc0 = (A[0] + R[0]) * EGO + D[0] * EGE;
      float ucs = __shfl(uc0, lanep1, 64);
      #pragma unroll
      for (int s = 0; s < 8; ++s) {
        float dnv;
        if (s == 7) dnv = is63 ? 0.0f : ucs;
        else {
          dnv = (A[s + 1] + R[s + 1]) * EGO + D[s + 1] * EGE;
          if (s == 6) dnv = is63 ? 0.0f : dnv;
        }
        const float rt = A[s] * EGO + R[s] * EGE;
        const bool val  = (p   <= PO_[s]);
        const bool valS = (pm1 <= PO_[s]);
        const float esg = val ? esO[s] : 0.0f;
        const float al  = esg * (SO[s] + one);
        const float pav = valS ? SO[s] : 0.0f;
        const float pa  = pav * esO[s];
        if ((s & 3) == 0) ac0 += pa; else if ((s & 3) == 1) ac1 += pa;
        else if ((s & 3) == 2) ac2 += pa; else ac3 += pa;
        const float s3 = al + rt + dnv;
        SO[s] = s3;
        A[s] = al; R[s] = rt; D[s] = dnv;
      }

      float esOn[8];
      #pragma unroll
      for (int s = 0; s < 8; ++s)
        esOn[s] = EPT[tgN[s] + esWb + (((7 - s + t + 1) & 7) << 7) + ((7 - s + t + 1) >> 3)];

      #pragma unroll
      for (int s = 0; s < 8; ++s) { tgO[s] = tgN[s]; esE[s] = esEn[s]; esO[s] = esOn[s]; }
    }
    ++esWb; ++tgWb;

    if ((b2 & 1) == 0) {
      float mx = fmaxf(SE[0], SO[0]);
      #pragma unroll
      for (int s = 1; s < 8; ++s) mx = fmaxf(mx, fmaxf(SE[s], SO[s]));
      mx = fmaxf(mx, __shfl_xor(mx, 1, 64));
      mx = fmaxf(mx, __shfl_xor(mx, 2, 64));
      mx = fmaxf(mx, __shfl_xor(mx, 4, 64));
      mcar = mx;
    } else {
      float mx = mcar;
      mx = fmaxf(mx, __shfl_xor(mx, 8, 64));
      mx = fmaxf(mx, __shfl_xor(mx, 16, 64));
      mx = fmaxf(mx, __shfl_xor(mx, 32, 64));
      const int ex = (int)((__float_as_uint(mx) >> 23) & 0xff);
      const float sc = __uint_as_float((unsigned)(253 - ex) << 23);
      Etot += ex - 126;
      #pragma unroll
      for (int s = 0; s < 8; ++s) {
        A[s] *= sc; R[s] *= sc; D[s] *= sc; SE[s] *= sc; SO[s] *= sc;
      }
      ac0 *= sc; ac1 *= sc; ac2 *= sc; ac3 *= sc;
      one *= sc;
    }
  }

  float atot = (ac0 + ac1) + (ac2 + ac3);
  #pragma unroll
  for (int off = 1; off < 64; off <<= 1) atot += __shfl_xor(atot, off, 64);
  if (lane == 0) partials[b] = __logf(atot) + (float)Etot * 0.69314718055994531f;
}

__global__ void sw_reduce_kernel(const float* __restrict__ partials, float* __restrict__ out) {
  const int t = (int)threadIdx.x;
  float v = (t < 32) ? partials[t] : 0.0f;
  for (int off = 32; off; off >>= 1) v += __shfl_down(v, off, 64);
  if (t == 0) out[0] = -v * (1.0f / 32.0f);
}

extern "C" void kernel_launch(void* const* d_in, const int* in_sizes, int n_in,
                              void* d_out, int out_size, void* d_ws, size_t ws_size,
                              hipStream_t stream) {
  const float* pred = (const float*)d_in[0];   // (32, 512, 4) fp32
  const int*   tgt  = (const int*)d_in[1];     // (32, 512) int32
  float* partials = (float*)d_ws;              // 32 floats at offset 0
  float* out = (float*)d_out;                  // scalar

  // X = 64 MiB at offset 1024, + 1 KiB guard for halo float3 over/under-reads.
  if (ws_size >= (size_t)67110912ULL) {
    float* X = (float*)((char*)d_ws + 1024);
    sw_pre_kernel<<<16384, 512, 0, stream>>>(pred, tgt, X);
    sw_dp_fast<<<32, 256, 0, stream>>>(X, partials);
  } else {
    sw_dp_kernel<<<32, 64, 0, stream>>>(pred, tgt, partials);
  }
  sw_reduce_kernel<<<1, 64, 0, stream>>>(partials, out);
}

// Round 9
// 167.026 us; speedup vs baseline: 1.5901x; 1.0263x over previous
//
#include <hip/hip_runtime.h>

#define EGO 0.018315638888734179f   // exp(-4)
#define EGE 0.36787944117144233f    // exp(-1)

__device__ __forceinline__ float escale(int k) {   // 2^k, clamped to normal range
  k = k < -126 ? -126 : (k > 127 ? 127 : k);
  return __uint_as_float((unsigned)(k + 127) << 23);
}

// =====================================================================
// Precompute diag-major gathered exp(scores), fp32:
// X[((b*512+p)*2+half)*512 + j]. Batch b's blocks land on XCD b%8.
// =====================================================================
__global__ __launch_bounds__(512) void sw_pre_kernel(const float* __restrict__ pred,
                                                     const int* __restrict__ tgt,
                                                     float* __restrict__ X) {
  const int q = (int)blockIdx.x;
  const int b = (q & 7) | ((q >> 12) << 3);
  const int p = (q >> 3) & 511;
  const int j = (int)threadIdx.x;
  const int a = 255 - j + p;
  const int c = p + j - 255;
  const bool av = (a >= 0) && (a < 512);
  float evn = 0.0f, odd = 0.0f;
  if (av && c >= 0 && c < 512)
    evn = __expf(pred[(((b << 9) + a) << 2) + tgt[(b << 9) + c]]);
  if (av && (c + 1) >= 0 && (c + 1) < 512)
    odd = __expf(pred[(((b << 9) + a) << 2) + tgt[(b << 9) + c + 1]]);
  float* base = X + (((size_t)((b << 9) | p)) << 10);
  base[j] = evn;
  base[512 + j] = odd;
}

// =====================================================================
// DP with halo: 4 waves/batch, 3 slots/lane, refresh every 32 iters.
// vs R8: immediate UNGATED pa (acc += s3*raw(p+1); raw(p+1)==0 exactly when
// cell p invalid, by precompute zeroing), no SEp/SOp, single cmp/substep,
// halo acc discarded statically at the end.
// =====================================================================
__global__ __launch_bounds__(256) void sw_dp_fast(const float* __restrict__ X,
                                                  float* __restrict__ partials) {
  __shared__ float SLDS[4096];            // [512 slots][8 floats] (5 used)
  __shared__ float MXl[4], SUMl[4];
  __shared__ int   ETl[4], ETf[4];

  const int tid = (int)threadIdx.x;
  const int w = tid >> 6, lane = tid & 63;
  const int b = (int)blockIdx.x;
  const float* Xb = X + ((size_t)b << 19);
  const int jld = 128 * w - 32 + 3 * lane;
  const int lanem1 = (lane + 63) & 63;
  const int lanep1 = (lane + 1) & 63;

  int jj[3], PEes[3], POes[3];
  bool isPh[3], wrS[3], rdh[3], phh[3], owS[3];
  #pragma unroll
  for (int s = 0; s < 3; ++s) {
    const int j = jld + s;
    jj[s] = j;
    const bool vj = (j >= 0) && (j < 512);
    const int pe = (255 + j < 765 - j) ? 255 + j : 765 - j;
    const int po = (255 + j < 764 - j) ? 255 + j : 764 - j;
    PEes[s] = vj ? pe : -1;
    POes[s] = vj ? po : -1;
    owS[s] = (j >= 128 * w) && (j < 128 * w + 128);
    isPh[s] = (j == 511);
    const int idx = 3 * lane + s;
    wrS[s] = (idx >= 32 && idx < 64) || (idx >= 128 && idx < 160);
    const bool halo = (idx < 32) || (idx >= 160);
    rdh[s] = halo && vj;
    phh[s] = halo && !vj;
  }

  float U[3], Dd[3], RC[3], SE[3], SO[3], DCt[3], RCe[3], acc[3];
  #pragma unroll
  for (int s = 0; s < 3; ++s) {
    U[s] = Dd[s] = RC[s] = SE[s] = SO[s] = 0.0f;
    acc[s] = 0.0f;
  }
  float one = 1.0f;
  int EtotW = 0;

  float3 evb[4], odb[4];

#define LOADP(par, p) do {                                                    \
    const float* row_ = Xb + (((size_t)(p)) << 10);                           \
    evb[par] = *(const float3*)(row_ + jld);                                  \
    odb[par] = *(const float3*)(row_ + 512 + jld);                            \
  } while (0)

#define SYNC() do {                                                           \
    asm volatile("s_waitcnt lgkmcnt(0)" ::: "memory");                        \
    __builtin_amdgcn_s_barrier();                                             \
    asm volatile("" ::: "memory");                                            \
  } while (0)

// EVENS: descending ss; shuffled rcS consumed last. pa = s3*rawnext (ungated).
#define EVSLOT(ss, raw, rawn, rightv, p) do {                                 \
    const float right = rightv;                                               \
    const float dn = U[ss] * EGO + Dd[ss] * EGE;                              \
    const float esg = ((p) <= PEes[ss]) ? (raw) : 0.0f;                       \
    const float al = esg * (SE[ss] + one);                                    \
    const float Un = al + right;                                              \
    const float s3 = Un + dn;                                                 \
    acc[ss] += s3 * (rawn);                                                   \
    SE[ss] = s3; U[ss] = Un; Dd[ss] = dn;                                     \
    float dc = Un * EGO + dn * EGE;                                           \
    dc = isPh[ss] ? 0.0f : dc;                                                \
    DCt[ss] = dc;                                                             \
    RCe[ss] = al * EGO + right * EGE;                                         \
  } while (0)

#define ODSLOT(ss, raw, rawn, dnvv, p) do {                                   \
    const float dnv = dnvv;                                                   \
    const float right = RCe[ss];                                              \
    const float esg = ((p) <= POes[ss]) ? (raw) : 0.0f;                       \
    const float al = esg * (SO[ss] + one);                                    \
    const float Un = al + right;                                              \
    const float s3 = Un + dnv;                                                \
    acc[ss] += s3 * (rawn);                                                   \
    SO[ss] = s3; U[ss] = Un; Dd[ss] = dnv;                                    \
    RCe[ss] = al * EGO + right * EGE;  /* becomes RC after loop */            \
  } while (0)

#define ITER(par, nxt, p) do {                                                \
    const float rcS_ = __shfl(RC[2], lanem1, 64);                             \
    EVSLOT(2, evb[par].z, evb[nxt].z, RC[1], p);                              \
    EVSLOT(1, evb[par].y, evb[nxt].y, RC[0], p);                              \
    EVSLOT(0, evb[par].x, evb[nxt].x, rcS_, p);                               \
    const float dcS_ = __shfl(DCt[0], lanep1, 64);                            \
    ODSLOT(0, odb[par].x, odb[nxt].x, DCt[1], p);                             \
    ODSLOT(1, odb[par].y, odb[nxt].y, DCt[2], p);                             \
    ODSLOT(2, odb[par].z, odb[nxt].z, dcS_, p);                               \
    RC[0] = RCe[0]; RC[1] = RCe[1]; RC[2] = RCe[2];                           \
  } while (0)

#define SOLO() do {                                                           \
    float mxl = 0.0f;                                                         \
    _Pragma("unroll")                                                         \
    for (int s = 0; s < 3; ++s) mxl = fmaxf(mxl, fmaxf(SE[s], SO[s]));        \
    _Pragma("unroll")                                                         \
    for (int off = 1; off < 64; off <<= 1) mxl = fmaxf(mxl, __shfl_xor(mxl, off, 64)); \
    const int ex = (int)((__float_as_uint(mxl) >> 23) & 0xff);                \
    if (ex > 0) {                                                             \
      const float sc = __uint_as_float((unsigned)(253 - ex) << 23);           \
      EtotW += ex - 126;                                                      \
      _Pragma("unroll")                                                       \
      for (int s = 0; s < 3; ++s) {                                           \
        U[s] *= sc; Dd[s] *= sc; RC[s] *= sc; SE[s] *= sc; SO[s] *= sc;       \
        acc[s] *= sc;                                                         \
      }                                                                       \
      one *= sc;                                                              \
    }                                                                         \
  } while (0)

#define REFRESH() do {                                                        \
    float mxl = 0.0f;                                                         \
    _Pragma("unroll")                                                         \
    for (int s = 0; s < 3; ++s) {                                             \
      float t_ = fmaxf(SE[s], SO[s]);                                         \
      mxl = fmaxf(mxl, owS[s] ? t_ : 0.0f);                                   \
    }                                                                         \
    _Pragma("unroll")                                                         \
    for (int off = 1; off < 64; off <<= 1) mxl = fmaxf(mxl, __shfl_xor(mxl, off, 64)); \
    if (lane == 0) { MXl[w] = mxl; ETl[w] = EtotW; }                          \
    _Pragma("unroll")                                                         \
    for (int s = 0; s < 3; ++s) if (wrS[s]) {                                 \
      float4 v4_; v4_.x = U[s]; v4_.y = Dd[s]; v4_.z = RC[s]; v4_.w = SE[s];  \
      *(float4*)(&SLDS[jj[s] * 8]) = v4_;                                     \
      SLDS[jj[s] * 8 + 4] = SO[s];                                            \
    }                                                                         \
    SYNC();                                                                   \
    int ets_[4]; float mxs_[4];                                               \
    _Pragma("unroll")                                                         \
    for (int q2 = 0; q2 < 4; ++q2) { mxs_[q2] = MXl[q2]; ets_[q2] = ETl[q2]; }\
    int tn_ = -2147483647;                                                    \
    _Pragma("unroll")                                                         \
    for (int q2 = 0; q2 < 4; ++q2) {                                          \
      if (mxs_[q2] > 0.0f) {                                                  \
        const int t2_ = ets_[q2] + (int)((__float_as_uint(mxs_[q2]) >> 23) & 0xff) - 126; \
        if (t2_ > tn_) tn_ = t2_;                                             \
      }                                                                       \
    }                                                                         \
    if (tn_ == -2147483647) tn_ = EtotW;                                      \
    { const int dd_ = EtotW - tn_;                                            \
      const float f1_ = escale(dd_ - dd_ / 2), f2_ = escale(dd_ / 2);         \
      _Pragma("unroll")                                                       \
      for (int s = 0; s < 3; ++s) {                                           \
        U[s] = U[s] * f1_ * f2_; Dd[s] = Dd[s] * f1_ * f2_;                   \
        RC[s] = RC[s] * f1_ * f2_; SE[s] = SE[s] * f1_ * f2_;                 \
        SO[s] = SO[s] * f1_ * f2_; acc[s] = acc[s] * f1_ * f2_;               \
      }                                                                       \
      one = one * f1_ * f2_; EtotW = tn_;                                     \
    }                                                                         \
    _Pragma("unroll")                                                         \
    for (int s = 0; s < 3; ++s) {                                             \
      if (rdh[s]) {                                                           \
        const int oww_ = (3 * lane + s < 32) ? (w - 1) : (w + 1);             \
        const int dd2_ = ets_[oww_] - EtotW;                                  \
        const float g1_ = escale(dd2_ - dd2_ / 2), g2_ = escale(dd2_ / 2);    \
        const float4 v4_ = *(const float4*)(&SLDS[jj[s] * 8]);                \
        U[s] = v4_.x * g1_ * g2_; Dd[s] = v4_.y * g1_ * g2_;                  \
        RC[s] = v4_.z * g1_ * g2_; SE[s] = v4_.w * g1_ * g2_;                 \
        SO[s] = SLDS[jj[s] * 8 + 4] * g1_ * g2_;                              \
      } else if (phh[s]) {                                                    \
        U[s] = 0.0f; Dd[s] = 0.0f; RC[s] = 0.0f; SE[s] = 0.0f; SO[s] = 0.0f;  \
      }                                                                       \
    }                                                                         \
    SYNC();                                                                   \
  } while (0)

  LOADP(0, 0); LOADP(1, 1); LOADP(2, 2); LOADP(3, 3);

  for (int qq = 0; qq < 127; ++qq) {
    const int p0 = qq << 2;
    ITER(0, 1, p0);     LOADP(0, p0 + 4);
    ITER(1, 2, p0 + 1); LOADP(1, p0 + 5);
    ITER(2, 3, p0 + 2); LOADP(2, p0 + 6);
    ITER(3, 0, p0 + 3); LOADP(3, p0 + 7);
    const int ph = qq & 7;
    if (ph == 3) SOLO();
    else if (ph == 7) REFRESH();
  }
  // tail: p = 508, 509, 510 (buffers hold 508..511; pa reads 509..511)
  ITER(0, 1, 508); ITER(1, 2, 509); ITER(2, 3, 510);

  // owned-slot acc only (halo slots computed real values redundantly)
  float atot = (owS[0] ? acc[0] : 0.0f) + (owS[1] ? acc[1] : 0.0f)
             + (owS[2] ? acc[2] : 0.0f);
  #pragma unroll
  for (int off = 1; off < 64; off <<= 1) atot += __shfl_xor(atot, off, 64);
  if (lane == 0) { SUMl[w] = atot; ETf[w] = EtotW; }
  __syncthreads();
  if (tid == 0) {
    int M = ETf[0];
    for (int q2 = 1; q2 < 4; ++q2) if (ETf[q2] > M) M = ETf[q2];
    float T = 0.0f;
    for (int q2 = 0; q2 < 4; ++q2) T += SUMl[q2] * escale(ETf[q2] - M);
    partials[b] = __logf(T) + (float)M * 0.69314718055994531f;
  }

#undef LOADP
#undef SYNC
#undef EVSLOT
#undef ODSLOT
#undef ITER
#undef SOLO
#undef REFRESH
}

// =====================================================================
// Fallback (R3, validated absmax 0.0): used when ws_size is too small.
// =====================================================================
__global__ __launch_bounds__(64) void sw_dp_kernel(const float* __restrict__ pred,
                                                   const int* __restrict__ tgt,
                                                   float* __restrict__ partials) {
  __shared__ float EPT[5120];
  __shared__ int   TG[1024];

  const int lane = (int)threadIdx.x;
  const int b = (int)blockIdx.x;

  #pragma unroll
  for (int k = 0; k < 80; ++k) EPT[lane + 64 * k] = 0.0f;
  #pragma unroll
  for (int k = 0; k < 16; ++k) {
    const int lc = lane + 64 * k;
    int vv = 4 << 10;
    if (lc >= 256 && lc < 768) vv = (tgt[b * 512 + (lc - 256)] << 10);
    TG[((lc & 7) << 7) + (lc >> 3)] = vv;
  }
  #pragma unroll
  for (int k = 0; k < 8; ++k) {
    const int a = lane + 64 * k;
    const float4 v = ((const float4*)pred)[b * 512 + a];
    const int base = ((a & 7) << 7) + 32 + (a >> 3);
    EPT[base]        = __expf(v.x);
    EPT[1024 + base] = __expf(v.y);
    EPT[2048 + base] = __expf(v.z);
    EPT[3072 + base] = __expf(v.w);
  }
  __syncthreads();

  int PE_[8], PO_[8];
  float A[8], R[8], D[8], SE[8], SO[8];
  #pragma unroll
  for (int s = 0; s < 8; ++s) {
    const int j = 8 * lane + s;
    const int pe1 = 255 + j, pe2 = 765 - j;
    PE_[s] = pe1 < pe2 ? pe1 : pe2;
    const int po2 = 764 - j;
    PO_[s] = pe1 < po2 ? pe1 : po2;
    A[s] = R[s] = D[s] = 0.0f;
    SE[s] = SO[s] = 0.0f;
  }
  float ac0 = 0.0f, ac1 = 0.0f, ac2 = 0.0f, ac3 = 0.0f;
  float one = 1.0f;
  int Etot = 0;
  const int lanem1 = (lane + 63) & 63;
  const int lanep1 = (lane + 1) & 63;
  const bool is0 = (lane == 0);
  const bool is63 = (lane == 63);

  int tgO[8], tgE0[8];
  float esE[8], esO[8];
  #pragma unroll
  for (int s = 0; s < 8; ++s) {
    tgE0[s] = TG[lane + (((s + 1) & 7) << 7) + ((s + 1) >> 3)];
    tgO[s]  = TG[lane + (((s + 2) & 7) << 7) + ((s + 2) >> 3)];
  }
  #pragma unroll
  for (int s = 0; s < 8; ++s) {
    esE[s] = EPT[tgE0[s] + (63 - lane) + ((7 - s) << 7)];
    esO[s] = EPT[tgO[s]  + (63 - lane) + ((7 - s) << 7)];
  }

  int esWb = 63 - lane;
  int tgWb = lane;
  float mcar = 0.0f;

  for (int b2 = 0; b2 < 64; ++b2) {
    #pragma unroll
    for (int t = 0; t < 8; ++t) {
      const int p = (b2 << 3) + t;
      const int pm1 = p - 1;

      int tgN[8];
      #pragma unroll
      for (int s = 0; s < 8; ++s)
        tgN[s] = TG[tgWb + (((s + 3 + t) & 7) << 7) + ((s + 3 + t) >> 3)];

      const float rc7 = A[7] * EGO + R[7] * EGE;
      float rcs = __shfl(rc7, lanem1, 64);
      float esEn[8];
      #pragma unroll
      for (int ss = 0; ss < 8; ++ss) {
        const int s = 7 - ss;
        float right;
        if (s == 0) right = is0 ? 0.0f : rcs;
        else        right = A[s - 1] * EGO + R[s - 1] * EGE;
        const float dn = (A[s] + R[s]) * EGO + D[s] * EGE;
        const bool val  = (p   <= PE_[s]);
        const bool valS = (pm1 <= PE_[s]);
        const float esg = val ? esE[s] : 0.0f;
        const float al  = esg * (SE[s] + one);
        const float pav = valS ? SE[s] : 0.0f;
        const float pa  = pav * esE[s];
        if ((s & 3) == 0) ac0 += pa; else if ((s & 3) == 1) ac1 += pa;
        else if ((s & 3) == 2) ac2 += pa; else ac3 += pa;
        const float s3 = al + right + dn;
        SE[s] = s3;
        A[s] = al; R[s] = right; D[s] = dn;
        esEn[s] = EPT[tgO[s] + esWb + (((7 - s + t + 1) & 7) << 7) + ((7 - s + t + 1) >> 3)];
      }

      const float uc0 = (A[0] + R[0]) * EGO + D[0] * EGE;
      float ucs = __shfl(uc0, lanep1, 64);
      #pragma unroll
      for (int s = 0; s < 8; ++s) {
        float dnv;
        if (s == 7) dnv = is63 ? 0.0f : ucs;
        else {
          dnv = (A[s + 1] + R[s + 1]) * EGO + D[s + 1] * EGE;
          if (s == 6) dnv = is63 ? 0.0f : dnv;
        }
        const float rt = A[s] * EGO + R[s] * EGE;
        const bool val  = (p   <= PO_[s]);
        const bool valS = (pm1 <= PO_[s]);
        const float esg = val ? esO[s] : 0.0f;
        const float al  = esg * (SO[s] + one);
        const float pav = valS ? SO[s] : 0.0f;
        const float pa  = pav * esO[s];
        if ((s & 3) == 0) ac0 += pa; else if ((s & 3) == 1) ac1 += pa;
        else if ((s & 3) == 2) ac2 += pa; else ac3 += pa;
        const float s3 = al + rt + dnv;
        SO[s] = s3;
        A[s] = al; R[s] = rt; D[s] = dnv;
      }

      float esOn[8];
      #pragma unroll
      for (int s = 0; s < 8; ++s)
        esOn[s] = EPT[tgN[s] + esWb + (((7 - s + t + 1) & 7) << 7) + ((7 - s + t + 1) >> 3)];

      #pragma unroll
      for (int s = 0; s < 8; ++s) { tgO[s] = tgN[s]; esE[s] = esEn[s]; esO[s] = esOn[s]; }
    }
    ++esWb; ++tgWb;

    if ((b2 & 1) == 0) {
      float mx = fmaxf(SE[0], SO[0]);
      #pragma unroll
      for (int s = 1; s < 8; ++s) mx = fmaxf(mx, fmaxf(SE[s], SO[s]));
      mx = fmaxf(mx, __shfl_xor(mx, 1, 64));
      mx = fmaxf(mx, __shfl_xor(mx, 2, 64));
      mx = fmaxf(mx, __shfl_xor(mx, 4, 64));
      mcar = mx;
    } else {
      float mx = mcar;
      mx = fmaxf(mx, __shfl_xor(mx, 8, 64));
      mx = fmaxf(mx, __shfl_xor(mx, 16, 64));
      mx = fmaxf(mx, __shfl_xor(mx, 32, 64));
      const int ex = (int)((__float_as_uint(mx) >> 23) & 0xff);
      const float sc = __uint_as_float((unsigned)(253 - ex) << 23);
      Etot += ex - 126;
      #pragma unroll
      for (int s = 0; s < 8; ++s) {
        A[s] *= sc; R[s] *= sc; D[s] *= sc; SE[s] *= sc; SO[s] *= sc;
      }
      ac0 *= sc; ac1 *= sc; ac2 *= sc; ac3 *= sc;
      one *= sc;
    }
  }

  float atot = (ac0 + ac1) + (ac2 + ac3);
  #pragma unroll
  for (int off = 1; off < 64; off <<= 1) atot += __shfl_xor(atot, off, 64);
  if (lane == 0) partials[b] = __logf(atot) + (float)Etot * 0.69314718055994531f;
}

__global__ void sw_reduce_kernel(const float* __restrict__ partials, float* __restrict__ out) {
  const int t = (int)threadIdx.x;
  float v = (t < 32) ? partials[t] : 0.0f;
  for (int off = 32; off; off >>= 1) v += __shfl_down(v, off, 64);
  if (t == 0) out[0] = -v * (1.0f / 32.0f);
}

extern "C" void kernel_launch(void* const* d_in, const int* in_sizes, int n_in,
                              void* d_out, int out_size, void* d_ws, size_t ws_size,
                              hipStream_t stream) {
  const float* pred = (const float*)d_in[0];   // (32, 512, 4) fp32
  const int*   tgt  = (const int*)d_in[1];     // (32, 512) int32
  float* partials = (float*)d_ws;              // 32 floats at offset 0
  float* out = (float*)d_out;                  // scalar

  // X = 64 MiB at offset 1024, + 1 KiB guard for halo float3 over/under-reads.
  if (ws_size >= (size_t)67110912ULL) {
    float* X = (float*)((char*)d_ws + 1024);
    sw_pre_kernel<<<16384, 512, 0, stream>>>(pred, tgt, X);
    sw_dp_fast<<<32, 256, 0, stream>>>(X, partials);
  } else {
    sw_dp_kernel<<<32, 64, 0, stream>>>(pred, tgt, partials);
  }
  sw_reduce_kernel<<<1, 64, 0, stream>>>(partials, out);
}